// Round 20
// baseline (396.709 us; speedup 1.0000x reference)
//
#include <hip/hip_runtime.h>

// ---------------------------------------------------------------------------
// SpikingMLP forward. bf16 MFMA GEMMs, split-precision weights (W_hi+W_lo,
// RNE split, converted during staging). R20 = R19 with BN 128->64:
// block tile 128x64, wave tile 32x32 (acc[2][2]), 2x grid (1024 blocks for
// the layer GEMMs) -> ~4-5 blocks/CU cross-block overlap (the only mechanism
// that has paid). Same proven swizzles, same per-element accumulation order
// -> bit-identical spike trains (absmax 0.00390625).
// ---------------------------------------------------------------------------

#define T_STEPS 8
#define BATCH 64
#define F0 32768
#define DIM 2048
#define NROWS 512
#define NC 1000

typedef __attribute__((ext_vector_type(8))) short short8;   // 8 bf16
typedef __attribute__((ext_vector_type(4))) float f32x4;    // MFMA acc

__device__ __forceinline__ unsigned short bf16_rne(float f) {
    unsigned int u = __float_as_uint(f);
    u += 0x7FFFu + ((u >> 16) & 1u);
    return (unsigned short)(u >> 16);
}

#define BM 128
#define BN 64
#define BK 64

__device__ __forceinline__ short8 lds_frag(const unsigned short* base, int row, int kb) {
    const int off = row * 128 + (kb ^ ((row & 7) << 4));
    return *(const short8*)((const char*)base + off);
}

__global__ __launch_bounds__(512) void gemm_splitk(
    const unsigned short* __restrict__ A, const float* __restrict__ W,
    float* __restrict__ part, int M, int N, int K, int Kpart, int Wrows)
{
    __shared__ unsigned short As[BM * BK];   // 16 KB
    __shared__ unsigned short Hs[BN * BK];   // 8 KB (W hi)
    __shared__ unsigned short Ls[BN * BK];   // 8 KB (W lo)

    // ---- XCD-chunked bijective remap (grid %8==0 at all call sites) ----
    const int gx = gridDim.x, gy = gridDim.y;
    const int nwg = gx * gy * gridDim.z;
    const int lid = blockIdx.x + gx * (blockIdx.y + gy * blockIdx.z);
    const int cpx = nwg >> 3;
    const int nid = (lid & 7) * cpx + (lid >> 3);
    const int bx  = nid % gx;
    const int by  = (nid / gx) % gy;
    const int kz  = nid / (gx * gy);

    const int tid  = threadIdx.x;
    const int lane = tid & 63;
    const int w    = tid >> 6;          // 0..7
    const int bm   = bx * BM;
    const int bn   = by * BN;
    const int ksteps = Kpart / BK;
    const int wm = (w >> 1) * 32;       // 4 M-quarters of 32
    const int wn = (w & 1) * 32;        // 2 N-halves of 32

    f32x4 acc[2][2] = {};

    for (int kt = 0; kt < ksteps; ++kt) {
        const int k0 = kz * Kpart + kt * BK;

        // ---- A tile: global_load_lds, linear dst + XOR'd src ----
#pragma unroll
        for (int c = 0; c < 2; ++c) {
            const int r    = w * 16 + c * 8 + (lane >> 3);
            const int colb = ((lane & 7) * 16) ^ ((r & 7) << 4);
            const char* src = (const char*)A + ((size_t)(bm + r) * K + k0) * 2 + colb;
            unsigned short* dst = &As[(w * 16 + c * 8) * BK];
            __builtin_amdgcn_global_load_lds(
                (const __attribute__((address_space(1))) void*)src,
                (__attribute__((address_space(3))) void*)dst, 16, 0, 0);
        }

        // ---- W tile: fp32 loads -> hi/lo bf16 split -> swizzled ds_write ----
        float4 wv[2];
#pragma unroll
        for (int i = 0; i < 2; ++i) {
            const int q  = tid + 512 * i;
            const int n  = q >> 4;           // 0..63
            const int c4 = q & 15;
            const int gn = min(bn + n, Wrows - 1);
            wv[i] = *(const float4*)&W[(size_t)gn * K + k0 + c4 * 4];
        }
#pragma unroll
        for (int i = 0; i < 2; ++i) {
            const int q  = tid + 512 * i;
            const int n  = q >> 4;
            const int c4 = q & 15;
            const float vf[4] = {wv[i].x, wv[i].y, wv[i].z, wv[i].w};
            unsigned short h[4], l[4];
#pragma unroll
            for (int e = 0; e < 4; ++e) {
                h[e] = bf16_rne(vf[e]);
                const float hf = __uint_as_float((unsigned int)h[e] << 16);
                l[e] = bf16_rne(vf[e] - hf);
            }
            const int off = n * 128 + ((c4 * 8) ^ ((n & 7) << 4));
            *(ushort4*)((char*)Hs + off) = make_ushort4(h[0], h[1], h[2], h[3]);
            *(ushort4*)((char*)Ls + off) = make_ushort4(l[0], l[1], l[2], l[3]);
        }

        __syncthreads();   // drains vmcnt (A dma) + lgkmcnt (W ds_writes)

        // ---- MFMA: acc += A*Whi + A*Wlo (pure LDS->MFMA) ----
#pragma unroll
        for (int kk = 0; kk < 2; ++kk) {
            const int kb = (kk * 32 + (lane >> 4) * 8) * 2;
            short8 a[2], bh[2], bl[2];
#pragma unroll
            for (int i = 0; i < 2; ++i)
                a[i] = lds_frag(As, wm + i * 16 + (lane & 15), kb);
#pragma unroll
            for (int i = 0; i < 2; ++i) {
                const int r = wn + i * 16 + (lane & 15);
                bh[i] = lds_frag(Hs, r, kb);
                bl[i] = lds_frag(Ls, r, kb);
            }
#pragma unroll
            for (int mi = 0; mi < 2; ++mi)
#pragma unroll
                for (int ni = 0; ni < 2; ++ni) {
                    acc[mi][ni] = __builtin_amdgcn_mfma_f32_16x16x32_bf16(
                        a[mi], bh[ni], acc[mi][ni], 0, 0, 0);
                    acc[mi][ni] = __builtin_amdgcn_mfma_f32_16x16x32_bf16(
                        a[mi], bl[ni], acc[mi][ni], 0, 0, 0);
                }
        }
        __syncthreads();
    }

    // ---- epilogue: partial store (C/D: col=lane&15, row=(lane>>4)*4+e) ----
    const size_t zoff = (size_t)kz * M * N;
#pragma unroll
    for (int mi = 0; mi < 2; ++mi) {
        const int gr0 = bm + wm + mi * 16 + (lane >> 4) * 4;
#pragma unroll
        for (int ni = 0; ni < 2; ++ni) {
            const int gc = bn + wn + ni * 16 + (lane & 15);
            if (gc < N) {
#pragma unroll
                for (int e = 0; e < 4; ++e) {
                    const int gr = gr0 + e;
                    if (gr < M) part[zoff + (size_t)gr * N + gc] = acc[mi][ni][e];
                }
            }
        }
    }
}

// part[KS][.][N] summed + bias -> out (fp32)
__global__ __launch_bounds__(256) void reduce_bias(
    const float* __restrict__ part, const float* __restrict__ bias,
    float* __restrict__ out, int KS, int MN, int N)
{
    const int i4 = blockIdx.x * 256 + threadIdx.x;
    if (i4 * 4 >= MN) return;
    float4 s = make_float4(0.f, 0.f, 0.f, 0.f);
    for (int z = 0; z < KS; ++z) {
        const float4 p = *(const float4*)&part[(size_t)z * MN + i4 * 4];
        s.x += p.x; s.y += p.y; s.z += p.z; s.w += p.w;
    }
    const int col = (i4 * 4) % N;
    const float4 b = *(const float4*)&bias[col];
    s.x += b.x; s.y += b.y; s.z += b.z; s.w += b.w;
    *(float4*)&out[(size_t)i4 * 4] = s;
}

// IF neuron on raw input, vectorized x4
__global__ __launch_bounds__(256) void if0_kernel(
    const float* __restrict__ x, unsigned short* __restrict__ s)
{
    const size_t id4 = ((size_t)blockIdx.x * 256 + threadIdx.x) * 4;
    float v0 = 0.f, v1 = 0.f, v2 = 0.f, v3 = 0.f;
#pragma unroll
    for (int t = 0; t < T_STEPS; ++t) {
        const size_t idx = (size_t)t * (BATCH * (size_t)F0) + id4;
        const float4 xv = *(const float4*)&x[idx];
        ushort4 o;
        v0 += xv.x; if (v0 >= 1.f) { o.x = 0x3F80; v0 = 0.f; } else o.x = 0;
        v1 += xv.y; if (v1 >= 1.f) { o.y = 0x3F80; v1 = 0.f; } else o.y = 0;
        v2 += xv.z; if (v2 >= 1.f) { o.z = 0x3F80; v2 = 0.f; } else o.z = 0;
        v3 += xv.w; if (v3 >= 1.f) { o.w = 0x3F80; v3 = 0.f; } else o.w = 0;
        *(ushort4*)&s[idx] = o;
    }
}

// Fused BN stats + BN apply + IF (stats order unchanged)
__global__ __launch_bounds__(256) void bn_stats_if(
    const float* __restrict__ z, const float* __restrict__ g,
    const float* __restrict__ be, unsigned short* __restrict__ s)
{
    __shared__ float ssum[4][64], ssq[4][64];
    __shared__ float ssc[64], ssh[64];
    const int l = threadIdx.x & 63;
    const int q = threadIdx.x >> 6;
    const int f = blockIdx.x * 64 + l;
    float sum = 0.f, sq = 0.f;
    for (int r = q; r < NROWS; r += 4) {
        const float v = z[(size_t)r * DIM + f];
        sum += v; sq += v * v;
    }
    ssum[q][l] = sum; ssq[q][l] = sq;
    __syncthreads();
    if (threadIdx.x < 64) {
        float ts = 0.f, tq = 0.f;
#pragma unroll
        for (int i = 0; i < 4; ++i) { ts += ssum[i][l]; tq += ssq[i][l]; }
        const float mean = ts * (1.0f / NROWS);
        const float var  = tq * (1.0f / NROWS) - mean * mean;
        const float inv  = rsqrtf(var + 1e-5f);
        const float sc   = g[f] * inv;
        ssc[l] = sc;
        ssh[l] = be[f] - mean * sc;
    }
    __syncthreads();
    const float sc = ssc[l];
    const float sh = ssh[l];
    for (int b = q; b < BATCH; b += 4) {
        const int id = b * DIM + f;
        float v = 0.f;
#pragma unroll
        for (int t = 0; t < T_STEPS; ++t) {
            const size_t idx = (size_t)t * (BATCH * DIM) + id;
            v += z[idx] * sc + sh;
            if (v >= 1.0f) { s[idx] = 0x3F80; v = 0.f; }
            else           { s[idx] = 0; }
        }
    }
}

// Layer-2 variant: emit only the T-mean of spikes (bf16, k/8 exact)
__global__ __launch_bounds__(256) void bn_stats_if_mean(
    const float* __restrict__ z, const float* __restrict__ g,
    const float* __restrict__ be, unsigned short* __restrict__ sbar)
{
    __shared__ float ssum[4][64], ssq[4][64];
    __shared__ float ssc[64], ssh[64];
    const int l = threadIdx.x & 63;
    const int q = threadIdx.x >> 6;
    const int f = blockIdx.x * 64 + l;
    float sum = 0.f, sq = 0.f;
    for (int r = q; r < NROWS; r += 4) {
        const float v = z[(size_t)r * DIM + f];
        sum += v; sq += v * v;
    }
    ssum[q][l] = sum; ssq[q][l] = sq;
    __syncthreads();
    if (threadIdx.x < 64) {
        float ts = 0.f, tq = 0.f;
#pragma unroll
        for (int i = 0; i < 4; ++i) { ts += ssum[i][l]; tq += ssq[i][l]; }
        const float mean = ts * (1.0f / NROWS);
        const float var  = tq * (1.0f / NROWS) - mean * mean;
        const float inv  = rsqrtf(var + 1e-5f);
        const float sc   = g[f] * inv;
        ssc[l] = sc;
        ssh[l] = be[f] - mean * sc;
    }
    __syncthreads();
    const float sc = ssc[l];
    const float sh = ssh[l];
    for (int b = q; b < BATCH; b += 4) {
        const int id = b * DIM + f;
        float v = 0.f;
        int cnt = 0;
#pragma unroll
        for (int t = 0; t < T_STEPS; ++t) {
            const size_t idx = (size_t)t * (BATCH * DIM) + id;
            v += z[idx] * sc + sh;
            if (v >= 1.0f) { cnt++; v = 0.f; }
        }
        sbar[id] = bf16_rne((float)cnt * 0.125f);
    }
}

extern "C" void kernel_launch(void* const* d_in, const int* in_sizes, int n_in,
                              void* d_out, int out_size, void* d_ws, size_t ws_size,
                              hipStream_t stream)
{
    const float* x    = (const float*)d_in[0];
    const float* W0   = (const float*)d_in[1];
    const float* b0   = (const float*)d_in[2];
    const float* g0   = (const float*)d_in[3];
    const float* be0  = (const float*)d_in[4];
    const float* W1   = (const float*)d_in[5];
    const float* b1   = (const float*)d_in[6];
    const float* g1   = (const float*)d_in[7];
    const float* be1  = (const float*)d_in[8];
    const float* W2   = (const float*)d_in[9];
    const float* b2   = (const float*)d_in[10];
    const float* g2   = (const float*)d_in[11];
    const float* be2  = (const float*)d_in[12];
    const float* Wout = (const float*)d_in[13];
    const float* bout = (const float*)d_in[14];
    float* out = (float*)d_out;
    (void)in_sizes; (void)n_in; (void)out_size; (void)ws_size;

    char* ws = (char*)d_ws;
    size_t off = 0;
    auto alloc = [&](size_t nbytes) {
        char* p = ws + off;
        off = (off + nbytes + 255) & ~(size_t)255;
        return p;
    };
    unsigned short* s0 = (unsigned short*)alloc((size_t)NROWS * F0 * 2);  // 33.5 MB
    unsigned short* s1 = (unsigned short*)alloc((size_t)NROWS * DIM * 2);
    unsigned short* s2 = (unsigned short*)alloc((size_t)NROWS * DIM * 2);
    unsigned short* sb = (unsigned short*)alloc((size_t)128 * DIM * 2);   // 128-row pad
    float* z    = (float*)alloc((size_t)NROWS * DIM * 4);
    float* part = (float*)alloc((size_t)8 * NROWS * DIM * 4);             // 33.5 MB (KS<=8 layer GEMMs; readout KS=32 needs 8.2 MB)

    const int MN = NROWS * DIM;

    // sn0 (vectorized x4)
    if0_kernel<<<(BATCH * (size_t)F0) / 4 / 256, 256, 0, stream>>>(x, s0);

    // layer 0: K=32768, KS=8  (grid 4*32*8=1024; ks=64)
    gemm_splitk<<<dim3(NROWS / BM, DIM / BN, 8), 512, 0, stream>>>(
        s0, W0, part, NROWS, DIM, F0, F0 / 8, DIM);
    reduce_bias<<<MN / 4 / 256, 256, 0, stream>>>(part, b0, z, 8, MN, DIM);
    bn_stats_if<<<DIM / 64, 256, 0, stream>>>(z, g0, be0, s1);

    // layer 1: K=2048, KS=8  (grid 1024; ks=4)
    gemm_splitk<<<dim3(NROWS / BM, DIM / BN, 8), 512, 0, stream>>>(
        s1, W1, part, NROWS, DIM, DIM, DIM / 8, DIM);
    reduce_bias<<<MN / 4 / 256, 256, 0, stream>>>(part, b1, z, 8, MN, DIM);
    bn_stats_if<<<DIM / 64, 256, 0, stream>>>(z, g1, be1, s2);

    // layer 2: fused bn+if+T-mean
    gemm_splitk<<<dim3(NROWS / BM, DIM / BN, 8), 512, 0, stream>>>(
        s2, W2, part, NROWS, DIM, DIM, DIM / 8, DIM);
    reduce_bias<<<MN / 4 / 256, 256, 0, stream>>>(part, b2, z, 8, MN, DIM);
    bn_stats_if_mean<<<DIM / 64, 256, 0, stream>>>(z, g2, be2, sb);

    // readout: [64,2048] x [1000,2048]^T, KS=32 (grid 1*16*32=512; ks=1)
    gemm_splitk<<<dim3(1, (NC + BN - 1) / BN, 32), 512, 0, stream>>>(
        sb, Wout, part, BATCH, NC, DIM, DIM / 32, NC);
    reduce_bias<<<(BATCH * NC / 4 + 255) / 256, 256, 0, stream>>>(
        part, bout, out, 32, BATCH * NC, NC);
}

// Round 21
// 381.903 us; speedup vs baseline: 1.0388x; 1.0388x over previous
//
#include <hip/hip_runtime.h>

// ---------------------------------------------------------------------------
// SpikingMLP forward — FINAL consolidated best (R19 config, 381 us measured).
// bf16 MFMA GEMMs with split-precision weights (W = W_hi + W_lo, RNE split,
// converted during staging; spikes exact in bf16 -> fp32-grade accuracy,
// absmax == fp32 baseline). 128x128x64 tile, 8 waves, single-buf 2-phase,
// zero-conflict XOR-swizzled LDS, global_load_lds A-path, XCD-chunked remap,
// split-K (KS=8 layers / 32 readout) + fused BN+IF epilogue chain.
// Structural search ledger (gemm0): 2-phase 178-207 us across occupancy
// 22-72% (MfmaUtil ~33% invariant); all deep-pipeline variants regressed
// (spill / 1-block-CU / reg-convert in MFMA chain). Raw dual-MFMA rate
// 1518 TF = 73% of the 16x16 ubench dual floor.
// ---------------------------------------------------------------------------

#define T_STEPS 8
#define BATCH 64
#define F0 32768
#define DIM 2048
#define NROWS 512
#define NC 1000

typedef __attribute__((ext_vector_type(8))) short short8;   // 8 bf16
typedef __attribute__((ext_vector_type(4))) float f32x4;    // MFMA acc

__device__ __forceinline__ unsigned short bf16_rne(float f) {
    unsigned int u = __float_as_uint(f);
    u += 0x7FFFu + ((u >> 16) & 1u);
    return (unsigned short)(u >> 16);
}

#define BM 128
#define BN 128
#define BK 64

__device__ __forceinline__ short8 lds_frag(const unsigned short* base, int row, int kb) {
    const int off = row * 128 + (kb ^ ((row & 7) << 4));
    return *(const short8*)((const char*)base + off);
}

__global__ __launch_bounds__(512) void gemm_splitk(
    const unsigned short* __restrict__ A, const float* __restrict__ W,
    float* __restrict__ part, int M, int N, int K, int Kpart, int Wrows)
{
    __shared__ unsigned short As[BM * BK];   // 16 KB
    __shared__ unsigned short Hs[BN * BK];   // 16 KB (W hi)
    __shared__ unsigned short Ls[BN * BK];   // 16 KB (W lo)

    // ---- XCD-chunked bijective remap (grid %8==0 at all call sites) ----
    const int gx = gridDim.x, gy = gridDim.y;
    const int nwg = gx * gy * gridDim.z;
    const int lid = blockIdx.x + gx * (blockIdx.y + gy * blockIdx.z);
    const int cpx = nwg >> 3;
    const int nid = (lid & 7) * cpx + (lid >> 3);
    const int bx  = nid % gx;
    const int by  = (nid / gx) % gy;
    const int kz  = nid / (gx * gy);

    const int tid  = threadIdx.x;
    const int lane = tid & 63;
    const int w    = tid >> 6;          // 0..7
    const int bm   = bx * BM;
    const int bn   = by * BN;
    const int ksteps = Kpart / BK;
    const int wm = (w >> 2) * 64;       // 2 M-halves
    const int wn = (w & 3) * 32;        // 4 N-quarters

    f32x4 acc[4][2] = {};

    for (int kt = 0; kt < ksteps; ++kt) {
        const int k0 = kz * Kpart + kt * BK;

        // ---- A tile: global_load_lds, linear dst + XOR'd src ----
#pragma unroll
        for (int c = 0; c < 2; ++c) {
            const int r    = w * 16 + c * 8 + (lane >> 3);
            const int colb = ((lane & 7) * 16) ^ ((r & 7) << 4);
            const char* src = (const char*)A + ((size_t)(bm + r) * K + k0) * 2 + colb;
            unsigned short* dst = &As[(w * 16 + c * 8) * BK];
            __builtin_amdgcn_global_load_lds(
                (const __attribute__((address_space(1))) void*)src,
                (__attribute__((address_space(3))) void*)dst, 16, 0, 0);
        }

        // ---- W tile: fp32 loads -> hi/lo bf16 split -> swizzled ds_write ----
        float4 wv[4];
#pragma unroll
        for (int i = 0; i < 4; ++i) {
            const int q  = tid + 512 * i;
            const int n  = q >> 4;
            const int c4 = q & 15;
            const int gn = min(bn + n, Wrows - 1);
            wv[i] = *(const float4*)&W[(size_t)gn * K + k0 + c4 * 4];
        }
#pragma unroll
        for (int i = 0; i < 4; ++i) {
            const int q  = tid + 512 * i;
            const int n  = q >> 4;
            const int c4 = q & 15;
            const float vf[4] = {wv[i].x, wv[i].y, wv[i].z, wv[i].w};
            unsigned short h[4], l[4];
#pragma unroll
            for (int e = 0; e < 4; ++e) {
                h[e] = bf16_rne(vf[e]);
                const float hf = __uint_as_float((unsigned int)h[e] << 16);
                l[e] = bf16_rne(vf[e] - hf);
            }
            const int off = n * 128 + ((c4 * 8) ^ ((n & 7) << 4));
            *(ushort4*)((char*)Hs + off) = make_ushort4(h[0], h[1], h[2], h[3]);
            *(ushort4*)((char*)Ls + off) = make_ushort4(l[0], l[1], l[2], l[3]);
        }

        __syncthreads();   // drains vmcnt (A dma) + lgkmcnt (W ds_writes)

        // ---- MFMA: acc += A*Whi + A*Wlo (pure LDS->MFMA) ----
#pragma unroll
        for (int kk = 0; kk < 2; ++kk) {
            const int kb = (kk * 32 + (lane >> 4) * 8) * 2;
            short8 a[4], bh[2], bl[2];
#pragma unroll
            for (int i = 0; i < 4; ++i)
                a[i] = lds_frag(As, wm + i * 16 + (lane & 15), kb);
#pragma unroll
            for (int i = 0; i < 2; ++i) {
                const int r = wn + i * 16 + (lane & 15);
                bh[i] = lds_frag(Hs, r, kb);
                bl[i] = lds_frag(Ls, r, kb);
            }
#pragma unroll
            for (int mi = 0; mi < 4; ++mi)
#pragma unroll
                for (int ni = 0; ni < 2; ++ni) {
                    acc[mi][ni] = __builtin_amdgcn_mfma_f32_16x16x32_bf16(
                        a[mi], bh[ni], acc[mi][ni], 0, 0, 0);
                    acc[mi][ni] = __builtin_amdgcn_mfma_f32_16x16x32_bf16(
                        a[mi], bl[ni], acc[mi][ni], 0, 0, 0);
                }
        }
        __syncthreads();
    }

    // ---- epilogue: partial store (C/D: col=lane&15, row=(lane>>4)*4+e) ----
    const size_t zoff = (size_t)kz * M * N;
#pragma unroll
    for (int mi = 0; mi < 4; ++mi) {
        const int gr0 = bm + wm + mi * 16 + (lane >> 4) * 4;
#pragma unroll
        for (int ni = 0; ni < 2; ++ni) {
            const int gc = bn + wn + ni * 16 + (lane & 15);
            if (gc < N) {
#pragma unroll
                for (int e = 0; e < 4; ++e) {
                    const int gr = gr0 + e;
                    if (gr < M) part[zoff + (size_t)gr * N + gc] = acc[mi][ni][e];
                }
            }
        }
    }
}

// part[KS][.][N] summed + bias -> out (fp32)
__global__ __launch_bounds__(256) void reduce_bias(
    const float* __restrict__ part, const float* __restrict__ bias,
    float* __restrict__ out, int KS, int MN, int N)
{
    const int i4 = blockIdx.x * 256 + threadIdx.x;
    if (i4 * 4 >= MN) return;
    float4 s = make_float4(0.f, 0.f, 0.f, 0.f);
    for (int z = 0; z < KS; ++z) {
        const float4 p = *(const float4*)&part[(size_t)z * MN + i4 * 4];
        s.x += p.x; s.y += p.y; s.z += p.z; s.w += p.w;
    }
    const int col = (i4 * 4) % N;
    const float4 b = *(const float4*)&bias[col];
    s.x += b.x; s.y += b.y; s.z += b.z; s.w += b.w;
    *(float4*)&out[(size_t)i4 * 4] = s;
}

// IF neuron on raw input, vectorized x4
__global__ __launch_bounds__(256) void if0_kernel(
    const float* __restrict__ x, unsigned short* __restrict__ s)
{
    const size_t id4 = ((size_t)blockIdx.x * 256 + threadIdx.x) * 4;
    float v0 = 0.f, v1 = 0.f, v2 = 0.f, v3 = 0.f;
#pragma unroll
    for (int t = 0; t < T_STEPS; ++t) {
        const size_t idx = (size_t)t * (BATCH * (size_t)F0) + id4;
        const float4 xv = *(const float4*)&x[idx];
        ushort4 o;
        v0 += xv.x; if (v0 >= 1.f) { o.x = 0x3F80; v0 = 0.f; } else o.x = 0;
        v1 += xv.y; if (v1 >= 1.f) { o.y = 0x3F80; v1 = 0.f; } else o.y = 0;
        v2 += xv.z; if (v2 >= 1.f) { o.z = 0x3F80; v2 = 0.f; } else o.z = 0;
        v3 += xv.w; if (v3 >= 1.f) { o.w = 0x3F80; v3 = 0.f; } else o.w = 0;
        *(ushort4*)&s[idx] = o;
    }
}

// Fused BN stats + BN apply + IF (stats order unchanged)
__global__ __launch_bounds__(256) void bn_stats_if(
    const float* __restrict__ z, const float* __restrict__ g,
    const float* __restrict__ be, unsigned short* __restrict__ s)
{
    __shared__ float ssum[4][64], ssq[4][64];
    __shared__ float ssc[64], ssh[64];
    const int l = threadIdx.x & 63;
    const int q = threadIdx.x >> 6;
    const int f = blockIdx.x * 64 + l;
    float sum = 0.f, sq = 0.f;
    for (int r = q; r < NROWS; r += 4) {
        const float v = z[(size_t)r * DIM + f];
        sum += v; sq += v * v;
    }
    ssum[q][l] = sum; ssq[q][l] = sq;
    __syncthreads();
    if (threadIdx.x < 64) {
        float ts = 0.f, tq = 0.f;
#pragma unroll
        for (int i = 0; i < 4; ++i) { ts += ssum[i][l]; tq += ssq[i][l]; }
        const float mean = ts * (1.0f / NROWS);
        const float var  = tq * (1.0f / NROWS) - mean * mean;
        const float inv  = rsqrtf(var + 1e-5f);
        const float sc   = g[f] * inv;
        ssc[l] = sc;
        ssh[l] = be[f] - mean * sc;
    }
    __syncthreads();
    const float sc = ssc[l];
    const float sh = ssh[l];
    for (int b = q; b < BATCH; b += 4) {
        const int id = b * DIM + f;
        float v = 0.f;
#pragma unroll
        for (int t = 0; t < T_STEPS; ++t) {
            const size_t idx = (size_t)t * (BATCH * DIM) + id;
            v += z[idx] * sc + sh;
            if (v >= 1.0f) { s[idx] = 0x3F80; v = 0.f; }
            else           { s[idx] = 0; }
        }
    }
}

// Layer-2 variant: emit only the T-mean of spikes (bf16, k/8 exact)
__global__ __launch_bounds__(256) void bn_stats_if_mean(
    const float* __restrict__ z, const float* __restrict__ g,
    const float* __restrict__ be, unsigned short* __restrict__ sbar)
{
    __shared__ float ssum[4][64], ssq[4][64];
    __shared__ float ssc[64], ssh[64];
    const int l = threadIdx.x & 63;
    const int q = threadIdx.x >> 6;
    const int f = blockIdx.x * 64 + l;
    float sum = 0.f, sq = 0.f;
    for (int r = q; r < NROWS; r += 4) {
        const float v = z[(size_t)r * DIM + f];
        sum += v; sq += v * v;
    }
    ssum[q][l] = sum; ssq[q][l] = sq;
    __syncthreads();
    if (threadIdx.x < 64) {
        float ts = 0.f, tq = 0.f;
#pragma unroll
        for (int i = 0; i < 4; ++i) { ts += ssum[i][l]; tq += ssq[i][l]; }
        const float mean = ts * (1.0f / NROWS);
        const float var  = tq * (1.0f / NROWS) - mean * mean;
        const float inv  = rsqrtf(var + 1e-5f);
        const float sc   = g[f] * inv;
        ssc[l] = sc;
        ssh[l] = be[f] - mean * sc;
    }
    __syncthreads();
    const float sc = ssc[l];
    const float sh = ssh[l];
    for (int b = q; b < BATCH; b += 4) {
        const int id = b * DIM + f;
        float v = 0.f;
        int cnt = 0;
#pragma unroll
        for (int t = 0; t < T_STEPS; ++t) {
            const size_t idx = (size_t)t * (BATCH * DIM) + id;
            v += z[idx] * sc + sh;
            if (v >= 1.0f) { cnt++; v = 0.f; }
        }
        sbar[id] = bf16_rne((float)cnt * 0.125f);
    }
}

extern "C" void kernel_launch(void* const* d_in, const int* in_sizes, int n_in,
                              void* d_out, int out_size, void* d_ws, size_t ws_size,
                              hipStream_t stream)
{
    const float* x    = (const float*)d_in[0];
    const float* W0   = (const float*)d_in[1];
    const float* b0   = (const float*)d_in[2];
    const float* g0   = (const float*)d_in[3];
    const float* be0  = (const float*)d_in[4];
    const float* W1   = (const float*)d_in[5];
    const float* b1   = (const float*)d_in[6];
    const float* g1   = (const float*)d_in[7];
    const float* be1  = (const float*)d_in[8];
    const float* W2   = (const float*)d_in[9];
    const float* b2   = (const float*)d_in[10];
    const float* g2   = (const float*)d_in[11];
    const float* be2  = (const float*)d_in[12];
    const float* Wout = (const float*)d_in[13];
    const float* bout = (const float*)d_in[14];
    float* out = (float*)d_out;
    (void)in_sizes; (void)n_in; (void)out_size; (void)ws_size;

    char* ws = (char*)d_ws;
    size_t off = 0;
    auto alloc = [&](size_t nbytes) {
        char* p = ws + off;
        off = (off + nbytes + 255) & ~(size_t)255;
        return p;
    };
    unsigned short* s0 = (unsigned short*)alloc((size_t)NROWS * F0 * 2);  // 33.5 MB
    unsigned short* s1 = (unsigned short*)alloc((size_t)NROWS * DIM * 2);
    unsigned short* s2 = (unsigned short*)alloc((size_t)NROWS * DIM * 2);
    unsigned short* sb = (unsigned short*)alloc((size_t)128 * DIM * 2);   // 128-row pad
    float* z    = (float*)alloc((size_t)NROWS * DIM * 4);
    float* part = (float*)alloc((size_t)8 * NROWS * DIM * 4);             // 33.5 MB (KS=8 layers; KSout=32 needs 8.2 MB)

    const int MN = NROWS * DIM;

    // sn0 (vectorized x4)
    if0_kernel<<<(BATCH * (size_t)F0) / 4 / 256, 256, 0, stream>>>(x, s0);

    // layer 0: K=32768, KS=8  (grid 4*16*8=512; ks=64)
    gemm_splitk<<<dim3(NROWS / BM, DIM / BN, 8), 512, 0, stream>>>(
        s0, W0, part, NROWS, DIM, F0, F0 / 8, DIM);
    reduce_bias<<<MN / 4 / 256, 256, 0, stream>>>(part, b0, z, 8, MN, DIM);
    bn_stats_if<<<DIM / 64, 256, 0, stream>>>(z, g0, be0, s1);

    // layer 1: K=2048, KS=8  (grid 512; ks=4)
    gemm_splitk<<<dim3(NROWS / BM, DIM / BN, 8), 512, 0, stream>>>(
        s1, W1, part, NROWS, DIM, DIM, DIM / 8, DIM);
    reduce_bias<<<MN / 4 / 256, 256, 0, stream>>>(part, b1, z, 8, MN, DIM);
    bn_stats_if<<<DIM / 64, 256, 0, stream>>>(z, g1, be1, s2);

    // layer 2: fused bn+if+T-mean
    gemm_splitk<<<dim3(NROWS / BM, DIM / BN, 8), 512, 0, stream>>>(
        s2, W2, part, NROWS, DIM, DIM, DIM / 8, DIM);
    reduce_bias<<<MN / 4 / 256, 256, 0, stream>>>(part, b2, z, 8, MN, DIM);
    bn_stats_if_mean<<<DIM / 64, 256, 0, stream>>>(z, g2, be2, sb);

    // readout: [64,2048] x [1000,2048]^T, KS=32 (grid 1*8*32=256; ks=1)
    gemm_splitk<<<dim3(1, (NC + BN - 1) / BN, 32), 512, 0, stream>>>(
        sb, Wout, part, BATCH, NC, DIM, DIM / 32, NC);
    reduce_bias<<<(BATCH * NC / 4 + 255) / 256, 256, 0, stream>>>(
        part, bout, out, 32, BATCH * NC, NC);
}